// Round 3
// baseline (138.674 us; speedup 1.0000x reference)
//
#include <hip/hip_runtime.h>

// LIF scan: z [B=32, T=1024, H=512] fp32 -> out [32,1024,512] fp32
//   V_t = 0.9*V_{t-1} + z[:,t-1,:] - (V_{t-1} > 1)      (exact fp32 op order)
//   out[:,t,:] = (V_t > 1) ? 1 : 0,  out[:,0,:] = 0
//
// R5 lesson: deeper pipelining (triple buffer + counted vmcnt) did NOT help
//   (42.7 -> 48.9 us). Phase time is not exposed-latency-bound.
// R6 theory: HBM is ACCESS-GRANULARITY bound. 256 blocks x 64 chains means
//   every read and write touches 256 B per 2 KB row (stride 2 KB) ->
//   DRAM row-activation bound ~2 TB/s (fill with contiguous streams: 6.4).
// R6 fix: 64 blocks x 256 chains (4 consumer + 8 producer waves, 768 thr).
//   Each block owns a contiguous 1 KB slice of every t-row: staging loads
//   are 1 KB contiguous per instruction, spike stores come from 4 waves
//   covering 1 KB per row. 4x granularity on both streams. LDS: 2 x 64 KB
//   double buffer (CH=64 rows x 1 KB), R4-style schedule (issue next chunk,
//   vmcnt(0), barrier) - 8 producer waves keep 64 KB/CU in flight.

#define LIF_H 512
#define LIF_T 1024
#define CH 64               // t-rows per phase
#define NPH 16              // 16*64 = 1024 rows staged; 1023 steps
#define NCONS 4
#define NPROD 8
#define NTHREADS ((NCONS + NPROD) * 64)   // 768
#define ROWF 256            // floats per LDS row (1 KB)

#define GLDS(gptr, lptr)                                                     \
    __builtin_amdgcn_global_load_lds(                                        \
        (const __attribute__((address_space(1))) void*)(gptr),               \
        (__attribute__((address_space(3))) void*)(lptr), 16, 0, 0)

__global__ __launch_bounds__(NTHREADS, 1) void lif_kernel(const float* __restrict__ z,
                                                          float* __restrict__ out) {
    extern __shared__ float lds[];      // 2 * CH * ROWF floats = 128 KB

    const int tid  = threadIdx.x;
    const int wave = tid >> 6;
    const int lane = tid & 63;
    const int bid  = blockIdx.x;        // 0..63
    const int b    = bid >> 1;          // batch
    const int h0   = (bid & 1) << 8;    // 0 or 256: 1 KB half-row slice

    const float* zb = z   + b * (LIF_T * LIF_H) + h0;   // row t slice = zb + t*512
    float*       ob = out + b * (LIF_T * LIF_H) + h0;

    // ---- prologue: producers stage chunk 0 into buf 0; consumers zero t=0 ----
    if (wave < NCONS) {
        ob[wave * 64 + lane] = 0.0f;
    } else {
        const int p = wave - NCONS;     // 0..7
#pragma unroll
        for (int j = 0; j < 8; ++j) {
            const int r = p * 8 + j;    // row within chunk
            GLDS(zb + r * LIF_H + lane * 4, &lds[r * ROWF]);
        }
        __builtin_amdgcn_sched_barrier(0);
        asm volatile("s_waitcnt vmcnt(0)" ::: "memory");
    }
    __builtin_amdgcn_s_barrier();

    float V = 0.0f;
    float r = 0.0f;                     // reset = previous spike (V0=0 -> 0)
    float* oc = ob + wave * 64 + lane;  // consumer store base (waves 0-3)

#define CHAIN(rb, s0, N)                                                     \
    _Pragma("unroll")                                                        \
    for (int i = 0; i < (N); ++i) {                                          \
        const float u  = __fadd_rn(__fmul_rn(0.9f, V), rb[i]);               \
        const float Vn = __fsub_rn(u, r);                                    \
        const float sp = (Vn > 1.0f) ? 1.0f : 0.0f;                          \
        oc[((s0) + i + 1) * LIF_H] = sp;                                     \
        r = sp;                                                              \
        V = Vn;                                                              \
    }

#pragma unroll 1
    for (int c = 0; c < NPH; ++c) {
        if (wave >= NCONS) {
            // ---- producers: stage chunk c+1 into the other buffer ----
            if (c + 1 < NPH) {
                const int p = wave - NCONS;
                float* dst = &lds[((c + 1) & 1) * (CH * ROWF)];
                const float* src = zb + (c + 1) * CH * LIF_H;
#pragma unroll
                for (int j = 0; j < 8; ++j) {
                    const int rr = p * 8 + j;
                    GLDS(src + rr * LIF_H + lane * 4, &dst[rr * ROWF]);
                }
                __builtin_amdgcn_sched_barrier(0);
                asm volatile("s_waitcnt vmcnt(0)" ::: "memory");
            }
        } else {
            // ---- consumers: scan chunk c from LDS ----
            const float* lb = &lds[(c & 1) * (CH * ROWF)];
            const int col = wave * 64 + lane;     // 0..255 within the 1 KB row
            const int s0 = c * CH;
            float rbA[32], rbB[32];
#pragma unroll
            for (int i = 0; i < 32; ++i) rbA[i] = lb[i * ROWF + col];
#pragma unroll
            for (int i = 0; i < 32; ++i) rbB[i] = lb[(32 + i) * ROWF + col];
            __builtin_amdgcn_sched_barrier(0);
            CHAIN(rbA, s0, 32);
            if (c < NPH - 1) {
                CHAIN(rbB, s0 + 32, 32);
            } else {
                CHAIN(rbB, s0 + 32, 31);          // steps 992..1022
            }
        }

        __builtin_amdgcn_s_barrier();
    }
}

extern "C" void kernel_launch(void* const* d_in, const int* in_sizes, int n_in,
                              void* d_out, int out_size, void* d_ws, size_t ws_size,
                              hipStream_t stream) {
    const float* z = (const float*)d_in[0];
    float* out = (float*)d_out;
    hipLaunchKernelGGL(lif_kernel, dim3(64), dim3(NTHREADS),
                       2 * CH * ROWF * sizeof(float), stream, z, out);
}

// Round 4
// 132.273 us; speedup vs baseline: 1.0484x; 1.0484x over previous
//
#include <hip/hip_runtime.h>

// LIF scan: z [B=32, T=1024, H=512] fp32 -> out [32,1024,512] fp32
//   V_t = 0.9*V_{t-1} + z[:,t-1,:] - (V_{t-1} > 1)      (exact fp32 op order)
//   out[:,t,:] = (V_t > 1) ? 1 : 0,  out[:,0,:] = 0
//
// R6 lesson: 64 fat blocks hit the per-CU streaming cap (64 x ~25 GB/s =
//   1.6 TB/s; measured 1.75). Granularity fix must keep all 256 CUs.
// R7: decouple write addressing from compute geometry.
//   All 256-CU variants plateau at 2.0-2.4 TB/s with 256B-per-2KB-stride
//   streams; the contiguous harness fill does 6.4 TB/s. So:
//   Pass 1 (lif_scan): R4's proven producer/consumer structure, but spikes
//     stored COMPACT: ws[bid][t][64] -> each block's write stream is fully
//     contiguous (256 KB). Only the z-read stays strided (half LLC-absorbed).
//   Pass 2 (lif_transpose): ws -> out layout shuffle. Each wave writes 1 KB
//     contiguous of an output row; reads are 4x256B contiguous panel rows
//     from LLC (64 MB ws << 256 MB LLC).
//   Fallback to direct strided stores if ws_size < 67.1 MB.

#define LIF_H 512
#define LIF_T 1024
#define CH 128            // timesteps per superchunk (32 KB per buffer)
#define NCH 8
#define NPROD 4
#define NTHREADS (64 * (1 + NPROD))
#define WS_FLOATS (256ull * LIF_T * 64)   // 16.78M floats = 67.1 MB

#define GLDS(gptr, lptr)                                                     \
    __builtin_amdgcn_global_load_lds(                                        \
        (const __attribute__((address_space(1))) void*)(gptr),               \
        (__attribute__((address_space(3))) void*)(lptr), 16, 0, 0)

// ---------------- pass 1: LIF scan, compact spike stores ----------------
__global__ __launch_bounds__(NTHREADS, 1) void lif_scan(const float* __restrict__ z,
                                                        float* __restrict__ ws) {
    __shared__ float lds[2][CH * 64];

    const int tid  = threadIdx.x;
    const int wave = tid >> 6;
    const int lane = tid & 63;
    const int bid  = blockIdx.x;        // 0..255 = b*8 + slice
    const int b    = bid >> 3;
    const int h0   = (bid & 7) << 6;

    const float* zb  = z  + b * (LIF_T * LIF_H) + h0;      // z row slice
    float*       wsb = ws + (size_t)bid * (LIF_T * 64);    // compact panel

    // prologue: stage chunk 0; consumer zeroes compact t=0 row
    if (wave == 0) {
        wsb[lane] = 0.0f;
    } else {
        const int p = wave - 1;
#pragma unroll
        for (int j = 0; j < 8; ++j) {
            const int r0 = p * 32 + j * 4;
            GLDS(zb + (r0 + (lane >> 4)) * LIF_H + (lane & 15) * 4,
                 &lds[0][r0 * 64]);
        }
        __builtin_amdgcn_sched_barrier(0);
        asm volatile("s_waitcnt vmcnt(0)" ::: "memory");
    }
    __builtin_amdgcn_s_barrier();

    float V = 0.0f;
    float r = 0.0f;                     // reset = previous spike (V0=0 -> 0)

#define LDRB(rb, sub)                                                        \
    _Pragma("unroll")                                                        \
    for (int i = 0; i < 32; ++i) rb[i] = lb[((sub) * 32 + i) * 64 + lane];

#define CHAINW(rb, s0, N)                                                    \
    _Pragma("unroll")                                                        \
    for (int i = 0; i < (N); ++i) {                                          \
        const float u  = __fadd_rn(__fmul_rn(0.9f, V), rb[i]);               \
        const float Vn = __fsub_rn(u, r);                                    \
        const float sp = (Vn > 1.0f) ? 1.0f : 0.0f;                          \
        wsb[((s0) + i + 1) * 64 + lane] = sp;                                \
        r = sp;                                                              \
        V = Vn;                                                              \
    }

#pragma unroll 1
    for (int c = 0; c < NCH; ++c) {
        if (wave > 0) {
            if (c + 1 < NCH) {
                const int p = wave - 1;
                float* dst = lds[(c + 1) & 1];
                const float* src = zb + (c + 1) * CH * LIF_H;
#pragma unroll
                for (int j = 0; j < 8; ++j) {
                    const int r0 = p * 32 + j * 4;
                    GLDS(src + (r0 + (lane >> 4)) * LIF_H + (lane & 15) * 4,
                         &dst[r0 * 64]);
                }
                __builtin_amdgcn_sched_barrier(0);
                asm volatile("s_waitcnt vmcnt(0)" ::: "memory");
            }
        } else {
            const float* lb = lds[c & 1];
            const int s0 = c * CH;
            float rbA[32], rbB[32];
            LDRB(rbA, 0);
            LDRB(rbB, 1);
            __builtin_amdgcn_sched_barrier(0);
            CHAINW(rbA, s0 + 0, 32);
            LDRB(rbA, 2);
            __builtin_amdgcn_sched_barrier(0);
            CHAINW(rbB, s0 + 32, 32);
            LDRB(rbB, 3);
            __builtin_amdgcn_sched_barrier(0);
            CHAINW(rbA, s0 + 64, 32);
            __builtin_amdgcn_sched_barrier(0);
            if (c < NCH - 1) {
                CHAINW(rbB, s0 + 96, 32);
            } else {
                CHAINW(rbB, s0 + 96, 31);   // steps 992..1022
            }
        }
        __builtin_amdgcn_s_barrier();
    }
}

// ---------------- pass 2: ws[b*8+s][t][64] -> out[b][t][512] ----------------
__global__ __launch_bounds__(256, 1) void lif_transpose(const float* __restrict__ ws,
                                                        float* __restrict__ out) {
    const int gid = blockIdx.x * 256 + threadIdx.x;   // 0..4194303 float4 items
    const int b   = gid >> 17;                        // 131072 items per batch
    const int rem = gid & 131071;
    const int t   = rem >> 7;                         // 128 float4 per out row
    const int h4  = rem & 127;
    const int s   = h4 >> 4;                          // source panel
    const int c4  = h4 & 15;                          // float4 within panel row
    const float4 v = *reinterpret_cast<const float4*>(
        ws + ((size_t)(b * 8 + s) * (LIF_T * 64) + t * 64 + c4 * 4));
    *reinterpret_cast<float4*>(
        out + ((size_t)b * (LIF_T * LIF_H) + (size_t)t * LIF_H + h4 * 4)) = v;
}

// ---------------- fallback: direct strided stores (R4 structure) ----------------
__global__ __launch_bounds__(NTHREADS, 1) void lif_direct(const float* __restrict__ z,
                                                          float* __restrict__ out) {
    __shared__ float lds[2][CH * 64];

    const int tid  = threadIdx.x;
    const int wave = tid >> 6;
    const int lane = tid & 63;
    const int bid  = blockIdx.x;
    const int b    = bid >> 3;
    const int h0   = (bid & 7) << 6;

    const float* zb = z   + b * (LIF_T * LIF_H) + h0;
    float*       ob = out + b * (LIF_T * LIF_H) + h0;

    if (wave == 0) {
        ob[lane] = 0.0f;
    } else {
        const int p = wave - 1;
#pragma unroll
        for (int j = 0; j < 8; ++j) {
            const int r0 = p * 32 + j * 4;
            GLDS(zb + (r0 + (lane >> 4)) * LIF_H + (lane & 15) * 4,
                 &lds[0][r0 * 64]);
        }
        __builtin_amdgcn_sched_barrier(0);
        asm volatile("s_waitcnt vmcnt(0)" ::: "memory");
    }
    __builtin_amdgcn_s_barrier();

    float V = 0.0f;
    float r = 0.0f;

#define CHAIND(rb, s0, N)                                                    \
    _Pragma("unroll")                                                        \
    for (int i = 0; i < (N); ++i) {                                          \
        const float u  = __fadd_rn(__fmul_rn(0.9f, V), rb[i]);               \
        const float Vn = __fsub_rn(u, r);                                    \
        const float sp = (Vn > 1.0f) ? 1.0f : 0.0f;                          \
        ob[((s0) + i + 1) * LIF_H + lane] = sp;                              \
        r = sp;                                                              \
        V = Vn;                                                              \
    }

#pragma unroll 1
    for (int c = 0; c < NCH; ++c) {
        if (wave > 0) {
            if (c + 1 < NCH) {
                const int p = wave - 1;
                float* dst = lds[(c + 1) & 1];
                const float* src = zb + (c + 1) * CH * LIF_H;
#pragma unroll
                for (int j = 0; j < 8; ++j) {
                    const int r0 = p * 32 + j * 4;
                    GLDS(src + (r0 + (lane >> 4)) * LIF_H + (lane & 15) * 4,
                         &dst[r0 * 64]);
                }
                __builtin_amdgcn_sched_barrier(0);
                asm volatile("s_waitcnt vmcnt(0)" ::: "memory");
            }
        } else {
            const float* lb = lds[c & 1];
            const int s0 = c * CH;
            float rbA[32], rbB[32];
            LDRB(rbA, 0);
            LDRB(rbB, 1);
            __builtin_amdgcn_sched_barrier(0);
            CHAIND(rbA, s0 + 0, 32);
            LDRB(rbA, 2);
            __builtin_amdgcn_sched_barrier(0);
            CHAIND(rbB, s0 + 32, 32);
            LDRB(rbB, 3);
            __builtin_amdgcn_sched_barrier(0);
            CHAIND(rbA, s0 + 64, 32);
            __builtin_amdgcn_sched_barrier(0);
            if (c < NCH - 1) {
                CHAIND(rbB, s0 + 96, 32);
            } else {
                CHAIND(rbB, s0 + 96, 31);
            }
        }
        __builtin_amdgcn_s_barrier();
    }
}

extern "C" void kernel_launch(void* const* d_in, const int* in_sizes, int n_in,
                              void* d_out, int out_size, void* d_ws, size_t ws_size,
                              hipStream_t stream) {
    const float* z = (const float*)d_in[0];
    float* out = (float*)d_out;
    if (ws_size >= WS_FLOATS * sizeof(float)) {
        float* ws = (float*)d_ws;
        hipLaunchKernelGGL(lif_scan, dim3(256), dim3(NTHREADS), 0, stream, z, ws);
        hipLaunchKernelGGL(lif_transpose, dim3(16384), dim3(256), 0, stream, ws, out);
    } else {
        hipLaunchKernelGGL(lif_direct, dim3(256), dim3(NTHREADS), 0, stream, z, out);
    }
}